// Round 15
// baseline (929.942 us; speedup 1.0000x reference)
//
#include <hip/hip_runtime.h>
#include <math.h>

// InfoNCE loss, K=3, SKIP=1, NEG=64
// z,c: (64,256,14,14) f32; Wk: (3,256,256) f32; neg_idx_k: (rows_k*64,) i32
// rows_k = 10752, 9856, 8960. row = (h*14+w)*64 + b.
//
// TWO launches: init (zero out + 3 grid-barrier counters), then ONE fused
// kernel, grid 1848 x 128, all blocks co-resident (LDS 17952 B -> 9/CU by
// LDS; launch_bounds(128,4) -> 128 VGPR -> 8/CU; 1848 <= 8*256). Hand-rolled
// grid barrier: device-scope atomic counter + acquire spin (per-XCD L2
// non-coherence handled by agent-scope atomics/fences).
// P1 prep (Wk->bf16, z->zt bf16, c->ct8 fp8) | bar | P2 proj (R14-verified
// M16 body: A-frags in regs, B staged per o-tile pair) | bar | P3 loss
// (R8-verified body, 16 tasks/block, partial per block) | bar | block 0
// reduces 1848 partials -> out.

typedef short bf16x8 __attribute__((ext_vector_type(8)));
typedef float f32x4 __attribute__((ext_vector_type(4)));

static __device__ __forceinline__ unsigned short f2bf(float f) {
    union { float f; unsigned int u; } x; x.f = f;
    unsigned int r = x.u + 0x7fffu + ((x.u >> 16) & 1u);   // RNE
    return (unsigned short)(r >> 16);
}

// float -> OCP e4m3fn (RNE, saturate to 448, subnormals handled)
static __device__ __forceinline__ unsigned char f2e4m3(float f) {
    union { float f; unsigned int u; } x; x.f = f;
    unsigned int s = (x.u >> 24) & 0x80u;
    float af = fabsf(f);
    if (af > 448.f) af = 448.f;
    x.f = af;
    unsigned int u = x.u;
    int e = (int)(u >> 23) - 127;
    unsigned int out;
    if (af == 0.f) {
        out = 0u;
    } else if (e < -6) {
        int mq = (int)rintf(af * 512.f);
        out = (mq >= 8) ? 0x08u : (unsigned int)mq;
    } else {
        unsigned int r = u + 0x7FFFFu + ((u >> 20) & 1u);
        int e2 = (int)(r >> 23) - 127;
        if (e2 > 8) out = 0x7Eu;
        else out = (unsigned int)(((e2 + 7) << 3) | ((r >> 20) & 7u));
    }
    return (unsigned char)(s | out);
}

// async global->LDS DMA: per-lane global addr, dest = uniform base + lane*4
static __device__ __forceinline__ void gload_lds4(const void* g, void* l) {
    __builtin_amdgcn_global_load_lds(
        (const __attribute__((address_space(1))) void*)g,
        (__attribute__((address_space(3))) void*)l, 4, 0, 0);
}

// grid barrier: counter pre-zeroed by init kernel; each use has its own
// counter (no sense reversal). Release fence + agent-scope RMW; acquire
// spin invalidates stale caches for the whole CU.
static __device__ __forceinline__ void grid_bar(int* cnt, int target) {
    __syncthreads();
    if (threadIdx.x == 0) {
        __threadfence();
        __hip_atomic_fetch_add(cnt, 1, __ATOMIC_ACQ_REL, __HIP_MEMORY_SCOPE_AGENT);
        while (__hip_atomic_load(cnt, __ATOMIC_ACQUIRE, __HIP_MEMORY_SCOPE_AGENT) < target)
            __builtin_amdgcn_s_sleep(2);
        __threadfence();
    }
    __syncthreads();
}

__global__ void init_kernel(float* out, int* cnt) {
    if (threadIdx.x == 0) { out[0] = 0.f; cnt[0] = 0; cnt[1] = 0; cnt[2] = 0; }
}

#define QSTR 528      // bf16 tile row stride: dword stride 132 -> free 2-way
#define ROWB 272      // fp8 gather row stride
#define LDSB 17952    // union: prep 12864 | proj 16896 | loss 17680+256+16
#define NBLK 1848

__global__ __launch_bounds__(128, 4)
void fused_kernel(const float* __restrict__ z, const float* __restrict__ c,
                  const float* __restrict__ Wk,
                  const int* __restrict__ n0, const int* __restrict__ n1,
                  const int* __restrict__ n2,
                  unsigned short* __restrict__ zt, unsigned char* __restrict__ ct8,
                  unsigned short* __restrict__ wkb, unsigned char* __restrict__ ztwk8,
                  float* __restrict__ part, int* __restrict__ cnt,
                  float* __restrict__ out) {
    __shared__ __align__(16) unsigned char L[LDSB];
    const int tid = threadIdx.x;
    const int blk = blockIdx.x;
    const int wv = tid >> 6, lane = tid & 63;
    const int m = lane & 15, kq = lane >> 4;

    // ================= P1: prep (R14-verified mapping, 128-thread remap) ===
    {
        int i = blk * 128 + tid;
        if (i < 196608) wkb[i] = f2bf(Wk[i]);

        float (*tile)[201] = (float(*)[201])L;   // 16*201*4 = 12864 B
        for (int u = blk; u < 2048; u += NBLK) {
            const bool isz = u < 1024;
            const int local = isz ? u : u - 1024;
            const float* src = isz ? z : c;
            const int b  = local & 63;
            const int c0 = (local >> 6) << 4;
            __syncthreads();
            for (int i2 = tid; i2 < 16 * 196; i2 += 128) {
                int cc = i2 / 196;
                int hw = i2 - cc * 196;
                tile[cc][hw] = src[(size_t)((b << 8) + c0 + cc) * 196 + hw];
            }
            __syncthreads();
            if (isz) {
                for (int i2 = tid; i2 < 196 * 16; i2 += 128) {
                    int hw = i2 >> 4, cc = i2 & 15;
                    zt[(size_t)((hw << 6) + b) * 256 + c0 + cc] = f2bf(tile[cc][hw]);
                }
            } else {
                for (int i2 = tid; i2 < 196 * 16; i2 += 128) {
                    int hw = i2 >> 4, cc = i2 & 15;
                    ct8[(size_t)((hw << 6) + b) * 256 + c0 + cc] = f2e4m3(tile[cc][hw]);
                }
            }
        }
    }
    grid_bar(cnt + 0, NBLK);

    // ================= P2: proj (R14-executed-and-verified body) ===========
    {
        const int u = blk;
        int k, lt;
        if (u < 672)       { k = 0; lt = u; }
        else if (u < 1288) { k = 1; lt = u - 672; }
        else               { k = 2; lt = u - 1288; }
        const int row0  = lt << 4;
        const int zrow0 = row0 + (k + 2) * 896;        // h' = h + (k_idx+2)
        unsigned char* zo = ztwk8 + (size_t)k * 10752 * 256;
        const unsigned char* zsrc = (const unsigned char*)zt + (size_t)zrow0 * 512;
        const unsigned char* wsrc = (const unsigned char*)wkb + (size_t)k * 131072;

        for (int i = tid; i < 512; i += 128) {          // stage A: 16 x 512 B
            int sb = i << 4;
            int r = sb >> 9, off = sb & 511;
            *(int4*)(L + r * QSTR + off) = *(const int4*)(zsrc + sb);
        }
        __syncthreads();
        bf16x8 af[8];                                   // A-frags -> 32 VGPRs
        #pragma unroll
        for (int kk = 0; kk < 8; ++kk)
            af[kk] = *(const bf16x8*)(L + m * QSTR + (kq << 4) + (kk << 6));
        __syncthreads();

        for (int it = 0; it < 8; ++it) {
            for (int i = tid; i < 1024; i += 128) {     // stage 2 B-tiles
                int sb = i << 4;
                int t2 = sb >> 13;
                int rem = sb & 8191;
                int r = rem >> 9, off = rem & 511;
                *(int4*)(L + t2 * 16 * QSTR + r * QSTR + off) =
                    *(const int4*)(wsrc + (size_t)(((it << 1) + t2) * 16 + r) * 512 + off);
            }
            __syncthreads();
            const int o0 = ((it << 1) + wv) << 4;
            const unsigned char* bb = L + wv * 16 * QSTR;
            f32x4 acc = {0.f, 0.f, 0.f, 0.f};
            #pragma unroll
            for (int kk = 0; kk < 8; ++kk) {
                bf16x8 bf = *(const bf16x8*)(bb + m * QSTR + (kq << 4) + (kk << 6));
                acc = __builtin_amdgcn_mfma_f32_16x16x32_bf16(af[kk], bf, acc, 0, 0, 0);
            }
            #pragma unroll
            for (int r = 0; r < 4; ++r)                 // D: col=m, row=kq*4+r
                zo[(size_t)(row0 + (kq << 2) + r) * 256 + o0 + m] = f2e4m3(acc[r]);
            __syncthreads();
        }
    }
    grid_bar(cnt + 1, NBLK);

    // ================= P3: loss (R8-verified body), 16 tasks/block =========
    unsigned char* slab  = L;                 // 65*272 = 17680
    unsigned char* ctx_s = L + 17680;         // 256
    float* sred = (float*)(L + 17936);        // 4 floats
    float lsum = 0.f;

    for (int ti = 0; ti < 16; ++ti) {
        const int t = blk + ti * NBLK;
        int k; const int* nb; int row; float wkf;
        if (t < 10752)      { k = 0; nb = n0; row = t;         wkf = 1.f / (3.f * 10752.f); }
        else if (t < 20608) { k = 1; nb = n1; row = t - 10752; wkf = 1.f / (3.f * 9856.f); }
        else                { k = 2; nb = n2; row = t - 20608; wkf = 1.f / (3.f * 8960.f); }
        const unsigned char* flat8 = ztwk8 + (size_t)k * 10752 * 256;

        const int myidx = nb[((size_t)row << 6) + lane];
        if (wv == 0) {
            gload_lds4(flat8 + (size_t)row * 256 + (lane << 2), slab);      // j=0
            #pragma unroll
            for (int j = 1; j <= 32; ++j) {
                int idx = __builtin_amdgcn_readlane(myidx, j - 1);
                gload_lds4(flat8 + (size_t)idx * 256 + (lane << 2), slab + j * ROWB);
            }
        } else {
            gload_lds4(ct8 + (size_t)row * 256 + (lane << 2), ctx_s);
            #pragma unroll
            for (int j = 33; j <= 64; ++j) {
                int idx = __builtin_amdgcn_readlane(myidx, j - 1);
                gload_lds4(flat8 + (size_t)idx * 256 + (lane << 2), slab + j * ROWB);
            }
        }
        __syncthreads();   // drains vmcnt (DMA) for the whole block

        f32x4 acc[3] = {};
        const int mt0 = (wv == 0) ? 0 : 3;
        int soff[3];
        #pragma unroll
        for (int q = 0; q < 3; ++q) {
            int slot = ((mt0 + q) << 4) + m;
            if (slot > 64) slot = 64;
            soff[q] = slot * ROWB + (kq << 3);
        }
        const unsigned char* cp = ctx_s + (kq << 3);
        #pragma unroll
        for (int kk = 0; kk < 8; ++kk) {
            long long bfrag = *(const long long*)(cp + (kk << 5));
            #pragma unroll
            for (int q = 0; q < 3; ++q) {
                if (q < 2 || wv == 0) {
                    long long afr = *(const long long*)(slab + soff[q] + (kk << 5));
                    acc[q] = __builtin_amdgcn_mfma_f32_16x16x32_fp8_fp8(
                        afr, bfrag, acc[q], 0, 0, 0);
                }
            }
        }

        float m_l = -1e30f;
        if (wv == 0) {
            #pragma unroll
            for (int q = 0; q < 3; ++q)
                #pragma unroll
                for (int r = 0; r < 4; ++r) m_l = fmaxf(m_l, acc[q][r]);
        } else {
            #pragma unroll
            for (int r = 0; r < 4; ++r) m_l = fmaxf(m_l, acc[0][r]);   // mt=3
            if (kq == 0) m_l = fmaxf(m_l, acc[1][0]);                  // slot 64
        }
        m_l = fmaxf(m_l, __shfl_xor(m_l, 16));
        m_l = fmaxf(m_l, __shfl_xor(m_l, 32));

        float s_l = 0.f;
        if (wv == 0) {
            #pragma unroll
            for (int q = 0; q < 3; ++q)
                #pragma unroll
                for (int r = 0; r < 4; ++r) s_l += __expf(acc[q][r] - m_l);
        } else {
            #pragma unroll
            for (int r = 0; r < 4; ++r) s_l += __expf(acc[0][r] - m_l);
            if (kq == 0) s_l += __expf(acc[1][0] - m_l);
        }
        s_l += __shfl_xor(s_l, 16);
        s_l += __shfl_xor(s_l, 32);

        float main_l = acc[0][0];   // valid at wv0 lane0 (slot 0)
        if (lane == 0) { sred[wv * 2] = m_l; sred[wv * 2 + 1] = s_l; }
        __syncthreads();
        if (tid == 0) {
            float m0 = sred[0], s0 = sred[1];
            float m1 = sred[2], s1 = sred[3];
            float mg = fmaxf(m0, m1);
            float sg = s0 * __expf(m0 - mg) + s1 * __expf(m1 - mg);
            float p0 = __expf(main_l - mg) / sg;
            lsum += -logf(p0 + 1e-11f) * wkf;
        }
    }
    if (tid == 0) part[blk] = lsum;
    grid_bar(cnt + 2, NBLK);

    // ================= P4: block 0 reduces 1848 partials -> out ============
    if (blk == 0) {
        float s = 0.f;
        for (int i = tid; i < NBLK; i += 128) s += part[i];
        #pragma unroll
        for (int off = 32; off >= 1; off >>= 1) s += __shfl_xor(s, off);
        float* w0 = (float*)L;
        if (lane == 0) w0[wv] = s;
        __syncthreads();
        if (tid == 0) out[0] = w0[0] + w0[1];
    }
}

extern "C" void kernel_launch(void* const* d_in, const int* in_sizes, int n_in,
                              void* d_out, int out_size, void* d_ws, size_t ws_size,
                              hipStream_t stream) {
    const float* z  = (const float*)d_in[0];
    const float* c  = (const float*)d_in[1];
    const float* Wk = (const float*)d_in[2];
    const int* n0 = (const int*)d_in[3];
    const int* n1 = (const int*)d_in[4];
    const int* n2 = (const int*)d_in[5];
    float* out = (float*)d_out;

    // ws: zt 6.42MB | wkb 384KB | ct8 3.21MB | ztwk8 8.26MB | part 7.4KB | cnt
    char* p = (char*)d_ws;
    unsigned short* zt    = (unsigned short*)p;   p += (size_t)196 * 64 * 256 * 2;
    unsigned short* wkb   = (unsigned short*)p;   p += (size_t)3 * 65536 * 2;
    unsigned char*  ct8   = (unsigned char*)p;    p += (size_t)196 * 64 * 256;
    unsigned char*  ztwk8 = (unsigned char*)p;    p += (size_t)3 * 10752 * 256;
    float*          part  = (float*)p;            p += (size_t)NBLK * 4;
    int*            cnt   = (int*)p;

    init_kernel<<<1, 64, 0, stream>>>(out, cnt);
    fused_kernel<<<NBLK, 128, 0, stream>>>(z, c, Wk, n0, n1, n2,
                                           zt, ct8, wkb, ztwk8, part, cnt, out);
}

// Round 16
// 163.973 us; speedup vs baseline: 5.6713x; 5.6713x over previous
//
#include <hip/hip_runtime.h>
#include <math.h>

// InfoNCE loss, K=3, SKIP=1, NEG=64
// z,c: (64,256,14,14) f32; Wk: (3,256,256) f32; neg_idx_k: (rows_k*64,) i32
// rows_k = 10752, 9856, 8960. row = (h*14+w)*64 + b.
//
// Pipeline (6 launches): prep, proj (R12-verified), loss x3 (per-k split of
// the R8/R12-verified body — diagnostic: drops the top-5 visibility
// threshold from 51us to ~18us so proj/prep can finally be measured), reduce.

typedef short bf16x8 __attribute__((ext_vector_type(8)));
typedef float f32x4 __attribute__((ext_vector_type(4)));

static __device__ __forceinline__ unsigned short f2bf(float f) {
    union { float f; unsigned int u; } x; x.f = f;
    unsigned int r = x.u + 0x7fffu + ((x.u >> 16) & 1u);   // RNE
    return (unsigned short)(r >> 16);
}

// float -> OCP e4m3fn (RNE, saturate to 448, subnormals handled)
static __device__ __forceinline__ unsigned char f2e4m3(float f) {
    union { float f; unsigned int u; } x; x.f = f;
    unsigned int s = (x.u >> 24) & 0x80u;
    float af = fabsf(f);
    if (af > 448.f) af = 448.f;
    x.f = af;
    unsigned int u = x.u;
    int e = (int)(u >> 23) - 127;
    unsigned int out;
    if (af == 0.f) {
        out = 0u;
    } else if (e < -6) {
        int mq = (int)rintf(af * 512.f);          // multiples of 2^-9
        out = (mq >= 8) ? 0x08u : (unsigned int)mq;
    } else {
        unsigned int r = u + 0x7FFFFu + ((u >> 20) & 1u);  // RNE, drop 20 bits
        int e2 = (int)(r >> 23) - 127;
        if (e2 > 8) out = 0x7Eu;                  // 448
        else out = (unsigned int)(((e2 + 7) << 3) | ((r >> 20) & 7u));
    }
    return (unsigned char)(s | out);
}

// async global->LDS DMA: per-lane global addr, dest = uniform base + lane*4
static __device__ __forceinline__ void gload_lds4(const void* g, void* l) {
    __builtin_amdgcn_global_load_lds(
        (const __attribute__((address_space(1))) void*)g,
        (__attribute__((address_space(3))) void*)l, 4, 0, 0);
}

// prep: blocks [0,768): Wk->bf16 (block0 also zeroes out[0]);
// [768,1792): z -> zt bf16 transposed; [1792,2816): c -> ct8 fp8 transposed.
__global__ __launch_bounds__(256)
void prep_kernel(const float* __restrict__ z, const float* __restrict__ c,
                 const float* __restrict__ Wk,
                 unsigned short* __restrict__ zt, unsigned char* __restrict__ ct8,
                 unsigned short* __restrict__ wkb, float* __restrict__ out) {
    __shared__ float tile[16][201];
    const int tid = threadIdx.x;
    int x = blockIdx.x;
    if (x < 768) {
        int i = x * 256 + tid;
        wkb[i] = f2bf(Wk[i]);
        if (x == 0 && tid == 0) out[0] = 0.f;
        return;
    }
    const bool isz = x < 1792;
    const int local = isz ? (x - 768) : (x - 1792);
    const float* src = isz ? z : c;
    const int b  = local & 63;
    const int c0 = (local >> 6) << 4;
    for (int i = tid; i < 16 * 196; i += 256) {
        int cc = i / 196;
        int hw = i - cc * 196;
        tile[cc][hw] = src[(size_t)((b << 8) + c0 + cc) * 196 + hw];
    }
    __syncthreads();
    if (isz) {
        for (int i = tid; i < 196 * 16; i += 256) {
            int hw = i >> 4, cc = i & 15;
            zt[(size_t)((hw << 6) + b) * 256 + c0 + cc] = f2bf(tile[cc][hw]);
        }
    } else {
        for (int i = tid; i < 196 * 16; i += 256) {
            int hw = i >> 4, cc = i & 15;
            ct8[(size_t)((hw << 6) + b) * 256 + c0 + cc] = f2e4m3(tile[cc][hw]);
        }
    }
}

// proj (R12-verified): ztwk8[k][row][o] = fp8(sum_c zt[zrow][c]*wk[k][o][c])
// Grid (8, 462), o-tile fast (A-tile L2-hot). Tile M=64 x N=32. PSTR 528.
#define PSTR 528
__global__ __launch_bounds__(256)
void proj_mfma_kernel(const unsigned short* __restrict__ zt,
                      const unsigned short* __restrict__ wkb,
                      unsigned char* __restrict__ ztwk) {
    __shared__ __align__(16) unsigned char smem[(64 + 32) * PSTR];  // 50688 B
    unsigned char* smA = smem;
    unsigned char* smB = smem + 64 * PSTR;

    int x = blockIdx.y;
    int k, hw;
    if (x < 168)      { k = 0; hw = x; }
    else if (x < 322) { k = 1; hw = x - 168; }
    else              { k = 2; hw = x - 322; }
    const int o0 = blockIdx.x << 5;
    const int row0  = hw << 6;
    const int zrow0 = row0 + (((k + 2) * 14) << 6);    // h' = h + (k_idx+2)
    unsigned char* zo = ztwk + (size_t)k * 10752 * 256;

    const int tid = threadIdx.x;
    const unsigned char* zsrc = (const unsigned char*)(zt + (size_t)zrow0 * 256);
    const unsigned char* bsrc = (const unsigned char*)(wkb + ((size_t)k << 16) + o0 * 256);

    #pragma unroll
    for (int i = 0; i < 8; ++i) {          // A: 32 KB contiguous
        int sb = ((i << 8) + tid) << 4;
        int r = sb >> 9, off = sb & 511;
        *(int4*)(smA + r * PSTR + off) = *(const int4*)(zsrc + sb);
    }
    #pragma unroll
    for (int i = 0; i < 4; ++i) {          // B: 16 KB contiguous
        int sb = ((i << 8) + tid) << 4;
        int r = sb >> 9, off = sb & 511;
        *(int4*)(smB + r * PSTR + off) = *(const int4*)(bsrc + sb);
    }
    __syncthreads();

    const int wv = tid >> 6, lane = tid & 63;
    const int m = lane & 15, kq = lane >> 4;
    f32x4 acc[2] = {};
    const unsigned short* aP  = (const unsigned short*)(smA + (size_t)((wv << 4) + m) * PSTR) + (kq << 3);
    const unsigned short* bP0 = (const unsigned short*)(smB + (size_t)m * PSTR) + (kq << 3);
    const unsigned short* bP1 = (const unsigned short*)(smB + (size_t)(16 + m) * PSTR) + (kq << 3);
    #pragma unroll
    for (int kk = 0; kk < 256; kk += 32) {
        bf16x8 af = *(const bf16x8*)(aP  + kk);
        bf16x8 b0 = *(const bf16x8*)(bP0 + kk);
        bf16x8 b1 = *(const bf16x8*)(bP1 + kk);
        acc[0] = __builtin_amdgcn_mfma_f32_16x16x32_bf16(af, b0, acc[0], 0, 0, 0);
        acc[1] = __builtin_amdgcn_mfma_f32_16x16x32_bf16(af, b1, acc[1], 0, 0, 0);
    }
    __syncthreads();
    unsigned char* cs = smA;               // [64 rows][40 B]
    #pragma unroll
    for (int nt = 0; nt < 2; ++nt)
        #pragma unroll
        for (int r = 0; r < 4; ++r)
            cs[(size_t)((wv << 4) + (kq << 2) + r) * 40 + (nt << 4) + m] =
                f2e4m3(acc[nt][r]);
    __syncthreads();
    {
        int r = tid >> 2, off = (tid & 3) << 3;
        unsigned long long v = *(const unsigned long long*)(cs + (size_t)r * 40 + off);
        *(unsigned long long*)(zo + (size_t)(row0 + r) * 256 + o0 + off) = v;
    }
}

// loss (R8/R12-verified body, per-k dispatch): one block (2 waves) per row.
// Wave0: DMA rows 0..32 + MFMA mt 0..2; wave1: DMA rows 33..64 + ctx +
// MFMA mt 3..4. Slots: 0 main, 1..64 negs, 65..79 pad (clamped).
#define ROWB 272
__global__ __launch_bounds__(128, 4)
void loss_mfma_kernel(const unsigned char* __restrict__ ct8,
                      const unsigned char* __restrict__ flat8,
                      const int* __restrict__ nb_base,
                      float* __restrict__ rowloss, float wk) {
    __shared__ __align__(16) unsigned char slab[65 * ROWB];   // 17680 B
    __shared__ __align__(16) unsigned char ctx_s[256];
    __shared__ float sred[2][2];
    const int tid = threadIdx.x;
    const int wv = tid >> 6, lane = tid & 63;
    const int m = lane & 15, kq = lane >> 4;

    const int row = blockIdx.x;
    const int myidx = nb_base[((size_t)row << 6) + lane];

    if (wv == 0) {
        gload_lds4(flat8 + (size_t)row * 256 + (lane << 2), slab);          // j=0
        #pragma unroll
        for (int j = 1; j <= 32; ++j) {
            int idx = __builtin_amdgcn_readlane(myidx, j - 1);
            gload_lds4(flat8 + (size_t)idx * 256 + (lane << 2), slab + j * ROWB);
        }
    } else {
        gload_lds4(ct8 + (size_t)row * 256 + (lane << 2), ctx_s);
        #pragma unroll
        for (int j = 33; j <= 64; ++j) {
            int idx = __builtin_amdgcn_readlane(myidx, j - 1);
            gload_lds4(flat8 + (size_t)idx * 256 + (lane << 2), slab + j * ROWB);
        }
    }
    __syncthreads();   // drains vmcnt (DMA) for the whole block

    f32x4 acc[3] = {};
    const int mt0 = (wv == 0) ? 0 : 3;
    int soff[3];
    #pragma unroll
    for (int t = 0; t < 3; ++t) {
        int slot = ((mt0 + t) << 4) + m;
        if (slot > 64) slot = 64;
        soff[t] = slot * ROWB + (kq << 3);
    }
    const unsigned char* cp = ctx_s + (kq << 3);
    #pragma unroll
    for (int kk = 0; kk < 8; ++kk) {
        long long bfrag = *(const long long*)(cp + (kk << 5));
        #pragma unroll
        for (int t = 0; t < 3; ++t) {
            if (t < 2 || wv == 0) {
                long long af = *(const long long*)(slab + soff[t] + (kk << 5));
                acc[t] = __builtin_amdgcn_mfma_f32_16x16x32_fp8_fp8(af, bfrag, acc[t], 0, 0, 0);
            }
        }
    }

    float m_l = -1e30f;
    if (wv == 0) {
        #pragma unroll
        for (int t = 0; t < 3; ++t)
            #pragma unroll
            for (int r = 0; r < 4; ++r) m_l = fmaxf(m_l, acc[t][r]);
    } else {
        #pragma unroll
        for (int r = 0; r < 4; ++r) m_l = fmaxf(m_l, acc[0][r]);   // mt=3
        if (kq == 0) m_l = fmaxf(m_l, acc[1][0]);                  // slot 64
    }
    m_l = fmaxf(m_l, __shfl_xor(m_l, 16));
    m_l = fmaxf(m_l, __shfl_xor(m_l, 32));

    float s_l = 0.f;
    if (wv == 0) {
        #pragma unroll
        for (int t = 0; t < 3; ++t)
            #pragma unroll
            for (int r = 0; r < 4; ++r) s_l += __expf(acc[t][r] - m_l);
    } else {
        #pragma unroll
        for (int r = 0; r < 4; ++r) s_l += __expf(acc[0][r] - m_l);
        if (kq == 0) s_l += __expf(acc[1][0] - m_l);
    }
    s_l += __shfl_xor(s_l, 16);
    s_l += __shfl_xor(s_l, 32);

    float main_l = acc[0][0];   // valid at wv0 lane0 (slot 0)
    if (lane == 0) { sred[wv][0] = m_l; sred[wv][1] = s_l; }
    __syncthreads();
    if (tid == 0) {
        float m0 = sred[0][0], s0 = sred[0][1];
        float m1 = sred[1][0], s1 = sred[1][1];
        float mg = fmaxf(m0, m1);
        float sg = s0 * __expf(m0 - mg) + s1 * __expf(m1 - mg);
        float p0 = __expf(main_l - mg) / sg;
        rowloss[row] = -logf(p0 + 1e-11f) * wk;
    }
}

// Sum rowloss[0..29568) -> out[0] (out zeroed in prep)
__global__ __launch_bounds__(256)
void reduce_kernel(const float* __restrict__ rl, float* __restrict__ out) {
    float s = 0.f;
    const int stride = gridDim.x * blockDim.x;
    for (int i = blockIdx.x * blockDim.x + threadIdx.x; i < 29568; i += stride)
        s += rl[i];
    #pragma unroll
    for (int off = 32; off >= 1; off >>= 1) s += __shfl_xor(s, off);
    if ((threadIdx.x & 63) == 0) atomicAdd(out, s);
}

extern "C" void kernel_launch(void* const* d_in, const int* in_sizes, int n_in,
                              void* d_out, int out_size, void* d_ws, size_t ws_size,
                              hipStream_t stream) {
    const float* z  = (const float*)d_in[0];
    const float* c  = (const float*)d_in[1];
    const float* Wk = (const float*)d_in[2];
    const int* negs[3] = {(const int*)d_in[3], (const int*)d_in[4], (const int*)d_in[5]};
    float* out = (float*)d_out;

    char* p = (char*)d_ws;
    unsigned short* zt      = (unsigned short*)p;   p += (size_t)196 * 64 * 256 * 2;
    unsigned short* wkb     = (unsigned short*)p;   p += (size_t)3 * 65536 * 2;
    unsigned char*  ct8     = (unsigned char*)p;    p += (size_t)196 * 64 * 256;
    unsigned char*  ztwk8   = (unsigned char*)p;    p += (size_t)3 * 10752 * 256;
    float*          rowloss = (float*)p;

    prep_kernel<<<2816, 256, 0, stream>>>(z, c, Wk, zt, ct8, wkb, out);
    proj_mfma_kernel<<<dim3(8, 462), 256, 0, stream>>>(zt, wkb, ztwk8);

    const int rowsA[3] = {10752, 9856, 8960};
    const int baseA[3] = {0, 10752, 20608};
    for (int k = 0; k < 3; ++k) {
        loss_mfma_kernel<<<rowsA[k], 128, 0, stream>>>(
            ct8, ztwk8 + (size_t)k * 10752 * 256, negs[k],
            rowloss + baseA[k], 1.f / (3.f * rowsA[k]));
    }
    reduce_kernel<<<32, 256, 0, stream>>>(rowloss, out);
}

// Round 17
// 158.154 us; speedup vs baseline: 5.8800x; 1.0368x over previous
//
#include <hip/hip_runtime.h>
#include <math.h>

// InfoNCE loss, K=3, SKIP=1, NEG=64
// z,c: (64,256,14,14) f32; Wk: (3,256,256) f32; neg_idx_k: (rows_k*64,) i32
// rows_k = 10752, 9856, 8960. row = (h*14+w)*64 + b.
//
// Pipeline (4 launches): prep (z->zt bf16, c->ct8 fp8, zero out), proj
// (R12-verified GEMM; Wk f32 cast to bf16 on the fly during B-staging),
// loss (R8/R12-verified single dispatch — TA-segment floor ~51us), reduce.
//
// Measured context (R16): the harness's 256MiB 0xAA workspace re-poison
// (~43us at 6.2TB/s) + input restores precede our kernels on-stream every
// replay; that is the bulk of the non-kernel time and is not controllable.

typedef short bf16x8 __attribute__((ext_vector_type(8)));
typedef float f32x4 __attribute__((ext_vector_type(4)));

static __device__ __forceinline__ unsigned short f2bf(float f) {
    union { float f; unsigned int u; } x; x.f = f;
    unsigned int r = x.u + 0x7fffu + ((x.u >> 16) & 1u);   // RNE
    return (unsigned short)(r >> 16);
}

// float -> OCP e4m3fn (RNE, saturate to 448, subnormals handled)
static __device__ __forceinline__ unsigned char f2e4m3(float f) {
    union { float f; unsigned int u; } x; x.f = f;
    unsigned int s = (x.u >> 24) & 0x80u;
    float af = fabsf(f);
    if (af > 448.f) af = 448.f;
    x.f = af;
    unsigned int u = x.u;
    int e = (int)(u >> 23) - 127;
    unsigned int out;
    if (af == 0.f) {
        out = 0u;
    } else if (e < -6) {
        int mq = (int)rintf(af * 512.f);          // multiples of 2^-9
        out = (mq >= 8) ? 0x08u : (unsigned int)mq;
    } else {
        unsigned int r = u + 0x7FFFFu + ((u >> 20) & 1u);  // RNE, drop 20 bits
        int e2 = (int)(r >> 23) - 127;
        if (e2 > 8) out = 0x7Eu;                  // 448
        else out = (unsigned int)(((e2 + 7) << 3) | ((r >> 20) & 7u));
    }
    return (unsigned char)(s | out);
}

// async global->LDS DMA: per-lane global addr, dest = uniform base + lane*4
static __device__ __forceinline__ void gload_lds4(const void* g, void* l) {
    __builtin_amdgcn_global_load_lds(
        (const __attribute__((address_space(1))) void*)g,
        (__attribute__((address_space(3))) void*)l, 4, 0, 0);
}

// prep: blocks [0,1024): z -> zt bf16 transposed (block0 zeroes out[0]);
// [1024,2048): c -> ct8 fp8 transposed.
__global__ __launch_bounds__(256)
void prep_kernel(const float* __restrict__ z, const float* __restrict__ c,
                 unsigned short* __restrict__ zt, unsigned char* __restrict__ ct8,
                 float* __restrict__ out) {
    __shared__ float tile[16][201];
    const int tid = threadIdx.x;
    int x = blockIdx.x;
    if (x == 0 && tid == 0) out[0] = 0.f;
    const bool isz = x < 1024;
    const int local = isz ? x : (x - 1024);
    const float* src = isz ? z : c;
    const int b  = local & 63;
    const int c0 = (local >> 6) << 4;
    for (int i = tid; i < 16 * 196; i += 256) {
        int cc = i / 196;
        int hw = i - cc * 196;
        tile[cc][hw] = src[(size_t)((b << 8) + c0 + cc) * 196 + hw];
    }
    __syncthreads();
    if (isz) {
        for (int i = tid; i < 196 * 16; i += 256) {
            int hw = i >> 4, cc = i & 15;
            zt[(size_t)((hw << 6) + b) * 256 + c0 + cc] = f2bf(tile[cc][hw]);
        }
    } else {
        for (int i = tid; i < 196 * 16; i += 256) {
            int hw = i >> 4, cc = i & 15;
            ct8[(size_t)((hw << 6) + b) * 256 + c0 + cc] = f2e4m3(tile[cc][hw]);
        }
    }
}

// proj (R12-verified): ztwk8[k][row][o] = fp8(sum_c zt[zrow][c]*Wk[k][o][c])
// Grid (8, 462), o-tile fast (A-tile L2-hot). Tile M=64 x N=32. PSTR 528.
// B-staging reads Wk f32 directly and converts to bf16 into LDS (no wkb).
#define PSTR 528
__global__ __launch_bounds__(256)
void proj_mfma_kernel(const unsigned short* __restrict__ zt,
                      const float* __restrict__ Wk,
                      unsigned char* __restrict__ ztwk) {
    __shared__ __align__(16) unsigned char smem[(64 + 32) * PSTR];  // 50688 B
    unsigned char* smA = smem;
    unsigned char* smB = smem + 64 * PSTR;

    int x = blockIdx.y;
    int k, hw;
    if (x < 168)      { k = 0; hw = x; }
    else if (x < 322) { k = 1; hw = x - 168; }
    else              { k = 2; hw = x - 322; }
    const int o0 = blockIdx.x << 5;
    const int row0  = hw << 6;
    const int zrow0 = row0 + (((k + 2) * 14) << 6);    // h' = h + (k_idx+2)
    unsigned char* zo = ztwk + (size_t)k * 10752 * 256;

    const int tid = threadIdx.x;
    const unsigned char* zsrc = (const unsigned char*)(zt + (size_t)zrow0 * 256);
    const float* wsrc = Wk + ((size_t)k << 16) + (size_t)o0 * 256;   // 32 rows f32

    #pragma unroll
    for (int i = 0; i < 8; ++i) {          // A: 32 KB contiguous bf16
        int sb = ((i << 8) + tid) << 4;
        int r = sb >> 9, off = sb & 511;
        *(int4*)(smA + r * PSTR + off) = *(const int4*)(zsrc + sb);
    }
    #pragma unroll
    for (int i = 0; i < 8; ++i) {          // B: 8192 f32 -> bf16 during stage
        int v = (i << 8) + tid;            // float4 index, 0..2047
        int e = v << 2;                    // element index
        int r = e >> 8, col = e & 255;
        float4 f = *(const float4*)(wsrc + e);
        ushort4 h = make_ushort4(f2bf(f.x), f2bf(f.y), f2bf(f.z), f2bf(f.w));
        *(ushort4*)(smB + r * PSTR + (col << 1)) = h;
    }
    __syncthreads();

    const int wv = tid >> 6, lane = tid & 63;
    const int m = lane & 15, kq = lane >> 4;
    f32x4 acc[2] = {};
    const unsigned short* aP  = (const unsigned short*)(smA + (size_t)((wv << 4) + m) * PSTR) + (kq << 3);
    const unsigned short* bP0 = (const unsigned short*)(smB + (size_t)m * PSTR) + (kq << 3);
    const unsigned short* bP1 = (const unsigned short*)(smB + (size_t)(16 + m) * PSTR) + (kq << 3);
    #pragma unroll
    for (int kk = 0; kk < 256; kk += 32) {
        bf16x8 af = *(const bf16x8*)(aP  + kk);
        bf16x8 b0 = *(const bf16x8*)(bP0 + kk);
        bf16x8 b1 = *(const bf16x8*)(bP1 + kk);
        acc[0] = __builtin_amdgcn_mfma_f32_16x16x32_bf16(af, b0, acc[0], 0, 0, 0);
        acc[1] = __builtin_amdgcn_mfma_f32_16x16x32_bf16(af, b1, acc[1], 0, 0, 0);
    }
    __syncthreads();
    unsigned char* cs = smA;               // [64 rows][40 B]
    #pragma unroll
    for (int nt = 0; nt < 2; ++nt)
        #pragma unroll
        for (int r = 0; r < 4; ++r)
            cs[(size_t)((wv << 4) + (kq << 2) + r) * 40 + (nt << 4) + m] =
                f2e4m3(acc[nt][r]);
    __syncthreads();
    {
        int r = tid >> 2, off = (tid & 3) << 3;
        unsigned long long v = *(const unsigned long long*)(cs + (size_t)r * 40 + off);
        *(unsigned long long*)(zo + (size_t)(row0 + r) * 256 + o0 + off) = v;
    }
}

// loss (R8/R12-verified, single dispatch, TA floor ~51us): one block
// (2 waves) per row. Wave0: DMA rows 0..32 + MFMA mt 0..2; wave1: DMA rows
// 33..64 + ctx + MFMA mt 3..4. Slots: 0 main, 1..64 negs, 65..79 pad.
#define ROWB 272
__global__ __launch_bounds__(128, 4)
void loss_mfma_kernel(const unsigned char* __restrict__ ct8,
                      const unsigned char* __restrict__ ztwk8,
                      const int* __restrict__ n0, const int* __restrict__ n1,
                      const int* __restrict__ n2, float* __restrict__ rowloss) {
    __shared__ __align__(16) unsigned char slab[65 * ROWB];   // 17680 B
    __shared__ __align__(16) unsigned char ctx_s[256];
    __shared__ float sred[2][2];
    const int tid = threadIdx.x;
    const int wv = tid >> 6, lane = tid & 63;
    const int m = lane & 15, kq = lane >> 4;

    int x = blockIdx.x;
    int k; const int* nb_base;
    if (x < 10752)      { k = 0; nb_base = n0; }
    else if (x < 20608) { k = 1; nb_base = n1; x -= 10752; }
    else                { k = 2; nb_base = n2; x -= 20608; }
    const int row = x;
    const unsigned char* flat8 = ztwk8 + (size_t)k * 10752 * 256;
    const float wk = (k == 0) ? (1.f / (3.f * 10752.f))
                   : (k == 1) ? (1.f / (3.f * 9856.f))
                              : (1.f / (3.f * 8960.f));
    const int rbase = (k == 0) ? 0 : (k == 1) ? 10752 : 20608;

    const int myidx = nb_base[((size_t)row << 6) + lane];

    if (wv == 0) {
        gload_lds4(flat8 + (size_t)row * 256 + (lane << 2), slab);          // j=0
        #pragma unroll
        for (int j = 1; j <= 32; ++j) {
            int idx = __builtin_amdgcn_readlane(myidx, j - 1);
            gload_lds4(flat8 + (size_t)idx * 256 + (lane << 2), slab + j * ROWB);
        }
    } else {
        gload_lds4(ct8 + (size_t)row * 256 + (lane << 2), ctx_s);
        #pragma unroll
        for (int j = 33; j <= 64; ++j) {
            int idx = __builtin_amdgcn_readlane(myidx, j - 1);
            gload_lds4(flat8 + (size_t)idx * 256 + (lane << 2), slab + j * ROWB);
        }
    }
    __syncthreads();   // drains vmcnt (DMA) for the whole block

    f32x4 acc[3] = {};
    const int mt0 = (wv == 0) ? 0 : 3;
    int soff[3];
    #pragma unroll
    for (int t = 0; t < 3; ++t) {
        int slot = ((mt0 + t) << 4) + m;
        if (slot > 64) slot = 64;
        soff[t] = slot * ROWB + (kq << 3);
    }
    const unsigned char* cp = ctx_s + (kq << 3);
    #pragma unroll
    for (int kk = 0; kk < 8; ++kk) {
        long long bfrag = *(const long long*)(cp + (kk << 5));
        #pragma unroll
        for (int t = 0; t < 3; ++t) {
            if (t < 2 || wv == 0) {
                long long af = *(const long long*)(slab + soff[t] + (kk << 5));
                acc[t] = __builtin_amdgcn_mfma_f32_16x16x32_fp8_fp8(af, bfrag, acc[t], 0, 0, 0);
            }
        }
    }

    float m_l = -1e30f;
    if (wv == 0) {
        #pragma unroll
        for (int t = 0; t < 3; ++t)
            #pragma unroll
            for (int r = 0; r < 4; ++r) m_l = fmaxf(m_l, acc[t][r]);
    } else {
        #pragma unroll
        for (int r = 0; r < 4; ++r) m_l = fmaxf(m_l, acc[0][r]);   // mt=3
        if (kq == 0) m_l = fmaxf(m_l, acc[1][0]);                  // slot 64
    }
    m_l = fmaxf(m_l, __shfl_xor(m_l, 16));
    m_l = fmaxf(m_l, __shfl_xor(m_l, 32));

    float s_l = 0.f;
    if (wv == 0) {
        #pragma unroll
        for (int t = 0; t < 3; ++t)
            #pragma unroll
            for (int r = 0; r < 4; ++r) s_l += __expf(acc[t][r] - m_l);
    } else {
        #pragma unroll
        for (int r = 0; r < 4; ++r) s_l += __expf(acc[0][r] - m_l);
        if (kq == 0) s_l += __expf(acc[1][0] - m_l);
    }
    s_l += __shfl_xor(s_l, 16);
    s_l += __shfl_xor(s_l, 32);

    float main_l = acc[0][0];   // valid at wv0 lane0 (slot 0)
    if (lane == 0) { sred[wv][0] = m_l; sred[wv][1] = s_l; }
    __syncthreads();
    if (tid == 0) {
        float m0 = sred[0][0], s0 = sred[0][1];
        float m1 = sred[1][0], s1 = sred[1][1];
        float mg = fmaxf(m0, m1);
        float sg = s0 * __expf(m0 - mg) + s1 * __expf(m1 - mg);
        float p0 = __expf(main_l - mg) / sg;
        rowloss[rbase + row] = -logf(p0 + 1e-11f) * wk;
    }
}

// Sum rowloss[0..29568) -> out[0] (out zeroed in prep)
__global__ __launch_bounds__(256)
void reduce_kernel(const float* __restrict__ rl, float* __restrict__ out) {
    float s = 0.f;
    const int stride = gridDim.x * blockDim.x;
    for (int i = blockIdx.x * blockDim.x + threadIdx.x; i < 29568; i += stride)
        s += rl[i];
    #pragma unroll
    for (int off = 32; off >= 1; off >>= 1) s += __shfl_xor(s, off);
    if ((threadIdx.x & 63) == 0) atomicAdd(out, s);
}

extern "C" void kernel_launch(void* const* d_in, const int* in_sizes, int n_in,
                              void* d_out, int out_size, void* d_ws, size_t ws_size,
                              hipStream_t stream) {
    const float* z  = (const float*)d_in[0];
    const float* c  = (const float*)d_in[1];
    const float* Wk = (const float*)d_in[2];
    const int* negs[3] = {(const int*)d_in[3], (const int*)d_in[4], (const int*)d_in[5]};
    float* out = (float*)d_out;

    char* p = (char*)d_ws;
    unsigned short* zt      = (unsigned short*)p;   p += (size_t)196 * 64 * 256 * 2;
    unsigned char*  ct8     = (unsigned char*)p;    p += (size_t)196 * 64 * 256;
    unsigned char*  ztwk8   = (unsigned char*)p;    p += (size_t)3 * 10752 * 256;
    float*          rowloss = (float*)p;

    prep_kernel<<<2048, 256, 0, stream>>>(z, c, zt, ct8, out);
    proj_mfma_kernel<<<dim3(8, 462), 256, 0, stream>>>(zt, Wk, ztwk8);
    loss_mfma_kernel<<<29568, 128, 0, stream>>>(ct8, ztwk8, negs[0], negs[1],
                                                negs[2], rowloss);
    reduce_kernel<<<32, 256, 0, stream>>>(rowloss, out);
}